// Round 8
// baseline (514.437 us; speedup 1.0000x reference)
//
#include <hip/hip_runtime.h>
#include <stdint.h>

typedef __bf16 bf16_t;
typedef __bf16 bf16x8 __attribute__((ext_vector_type(8)));
typedef __bf16 bf16x4 __attribute__((ext_vector_type(4)));
typedef float  f32x4  __attribute__((ext_vector_type(4)));

#define MFMA_BF16(a,b,c) __builtin_amdgcn_mfma_f32_16x16x32_bf16((a),(b),(c),0,0,0)

constexpr int kB = 4;
constexpr int kS = 4096;
constexpr int kD = 1024;
constexpr int kH = 16;
constexpr int kHKV = 4;
constexpr int kDH = 64;
constexpr int kChunk = 256;

// async global->LDS, 16B per lane; lds dest must be wave-uniform base (lane*16 added by HW)
__device__ __forceinline__ void gload_lds16(const bf16_t* g, bf16_t* l){
  __builtin_amdgcn_global_load_lds((const __attribute__((address_space(1))) void*)g,
                                   (__attribute__((address_space(3))) void*)l, 16, 0, 0);
}

// wave-internal LDS write->read fence (no cross-wave sync needed)
__device__ __forceinline__ void lds_fence(){
  asm volatile("s_waitcnt lgkmcnt(0)" ::: "memory");
  __builtin_amdgcn_sched_barrier(0);
}

// ---------------------------------------------------------------- f32 -> bf16
__global__ __launch_bounds__(256) void k_cvt_bf16(const float* __restrict__ in,
                                                  bf16_t* __restrict__ out, int n4){
  int i = blockIdx.x * 256 + threadIdx.x;
  if (i >= n4) return;
  float4 v = ((const float4*)in)[i];
  bf16x4 o;
  o[0] = (__bf16)v.x; o[1] = (__bf16)v.y; o[2] = (__bf16)v.z; o[3] = (__bf16)v.w;
  ((bf16x4*)out)[i] = o;
}

// ------------------------------------------------- W[K,N] f32 -> Wt[N,K] bf16
__global__ __launch_bounds__(256) void k_transpose_cvt(const float* __restrict__ W,
                                                       bf16_t* __restrict__ Wt,
                                                       int K, int N){
  __shared__ float t[32][33];
  int n0 = blockIdx.x * 32, k0 = blockIdx.y * 32;
  int tx = threadIdx.x & 31, ty = threadIdx.x >> 5;
#pragma unroll
  for (int i = 0; i < 4; i++){
    int kkk = ty + i*8;
    t[kkk][tx] = W[(size_t)(k0+kkk)*N + n0 + tx];
  }
  __syncthreads();
#pragma unroll
  for (int i = 0; i < 4; i++){
    int nn = ty + i*8;
    Wt[(size_t)(n0+nn)*K + k0 + tx] = (__bf16)t[tx][nn];
  }
}

// ------------------------------------- V [B*S, HKV*64] bf16 -> vT [B*256 rows][S] bf16
// out row (b*256 + col) holds V^T: vT[(b*256+hkv*64+dh)*4096 + s] = V[b,s,hkv,dh]
__global__ __launch_bounds__(256) void k_transpose_v(const bf16_t* __restrict__ V,
                                                     bf16_t* __restrict__ vT){
  __shared__ bf16_t t[32][36];
  int r0 = blockIdx.x * 32;              // global row (b*4096+s), 512 tiles
  int c0 = blockIdx.y * 32;              // col (hkv*64+dh), 8 tiles
  int tx = threadIdx.x & 31, ty = threadIdx.x >> 5;
  int b  = r0 >> 12, s0 = r0 & 4095;
#pragma unroll
  for (int i = 0; i < 4; i++)
    t[ty + i*8][tx] = V[(size_t)(r0 + ty + i*8)*256 + c0 + tx];
  __syncthreads();
#pragma unroll
  for (int i = 0; i < 4; i++){
    int cc = ty + i*8;
    vT[(size_t)(b*256 + c0 + cc)*4096 + s0 + tx] = t[tx][cc];
  }
}

// --------------------------------------------------------- GEMM: A[M,K]@Bt[N,K]^T + bias
// m97 structure: 128x128 tile, BK=64, linear LDS + (row&7) 16B-block XOR swizzle,
// global_load_lds width=16 staging. 4 waves (2x2), each wave 64x64 = 4x4 mfma frags.
template<bool BF16OUT>
__global__ __launch_bounds__(256) void k_gemm_bt(const bf16_t* __restrict__ A,
                                                 const bf16_t* __restrict__ Bt,
                                                 const float* __restrict__ bias,
                                                 void* __restrict__ outp,
                                                 int M, int N, int K){
  (void)M;
  __shared__ bf16_t Al[128*64];
  __shared__ bf16_t Bl[128*64];
  const int tid = threadIdx.x;
  const int lane = tid & 63;
  const int wave = tid >> 6;
  const int wm = wave >> 1, wn = wave & 1;
  const int bm = blockIdx.y, bn = blockIdx.x;
  const int l15 = lane & 15, l4 = lane >> 4;
  const int s_row = lane >> 3;
  const int s_bc  = lane & 7;
  const int s_colE = (s_bc ^ s_row) * 8;
  f32x4 acc[4][4];
#pragma unroll
  for (int a = 0; a < 4; a++)
#pragma unroll
    for (int b = 0; b < 4; b++)
#pragma unroll
      for (int r = 0; r < 4; r++) acc[a][b][r] = 0.f;

  for (int kt = 0; kt < K; kt += 64){
    __syncthreads();
#pragma unroll
    for (int i = 0; i < 4; i++){
      int rowA = (wave*4 + i)*8 + s_row;
      gload_lds16(A  + (size_t)(bm*128 + rowA)*K + kt + s_colE, &Al[(wave*4 + i)*512]);
      gload_lds16(Bt + (size_t)(bn*128 + rowA)*K + kt + s_colE, &Bl[(wave*4 + i)*512]);
    }
    __syncthreads();
#pragma unroll
    for (int ks = 0; ks < 2; ks++){
      bf16x8 af[4], bfr[4];
#pragma unroll
      for (int mt = 0; mt < 4; mt++){
        int row = wm*64 + mt*16 + l15;
        af[mt] = *(const bf16x8*)&Al[(row*64 + ks*32 + l4*8) ^ ((row & 7)*8)];
      }
#pragma unroll
      for (int nt = 0; nt < 4; nt++){
        int row = wn*64 + nt*16 + l15;
        bfr[nt] = *(const bf16x8*)&Bl[(row*64 + ks*32 + l4*8) ^ ((row & 7)*8)];
      }
#pragma unroll
      for (int mt = 0; mt < 4; mt++)
#pragma unroll
        for (int nt = 0; nt < 4; nt++)
          acc[mt][nt] = MFMA_BF16(af[mt], bfr[nt], acc[mt][nt]);
    }
  }
#pragma unroll
  for (int mt = 0; mt < 4; mt++){
#pragma unroll
    for (int nt = 0; nt < 4; nt++){
      int row0 = bm*128 + wm*64 + mt*16 + l4*4;
      int col  = bn*128 + wn*64 + nt*16 + l15;
      float bv = bias[col];
#pragma unroll
      for (int r = 0; r < 4; r++){
        float v = acc[mt][nt][r] + bv;
        if (BF16OUT) ((bf16_t*)outp)[(size_t)(row0 + r)*N + col] = (__bf16)v;
        else         ((float*)outp)[(size_t)(row0 + r)*N + col] = v;
      }
    }
  }
}

// -------------------------------------------- RMSNorm + RoPE (q and k), f32 -> bf16
__global__ __launch_bounds__(256) void k_norm_rope(const float* __restrict__ qin,
                                                   const float* __restrict__ kin,
                                                   const float* __restrict__ qw,
                                                   const float* __restrict__ kw,
                                                   const float* __restrict__ cosb,
                                                   const float* __restrict__ sinb,
                                                   bf16_t* __restrict__ qout,
                                                   bf16_t* __restrict__ kout){
  const int g = blockIdx.x * 16 + (threadIdx.x >> 4);
  const int ln = threadIdx.x & 15;
  const int NQ = (kB*kS) * kH;
  const float* src; bf16_t* dst; const float* w;
  int row;
  if (g < NQ){
    row = g >> 4; int head = g & 15;
    src = qin + (size_t)row*1024 + head*64;
    dst = qout + (size_t)row*1024 + head*64;
    w = qw;
  } else {
    int gk = g - NQ;
    row = gk >> 2; int head = gk & 3;
    src = kin + (size_t)row*256 + head*64;
    dst = kout + (size_t)row*256 + head*64;
    w = kw;
  }
  float t0 = src[ln], t1 = src[ln+16], t2 = src[ln+32], t3 = src[ln+48];
  float ss = t0*t0 + t1*t1 + t2*t2 + t3*t3;
  ss += __shfl_xor(ss, 1); ss += __shfl_xor(ss, 2);
  ss += __shfl_xor(ss, 4); ss += __shfl_xor(ss, 8);
  float rs = rsqrtf(ss * (1.0f/64.0f) + 1e-6f);
  t0 *= rs * w[ln];    t1 *= rs * w[ln+16];
  t2 *= rs * w[ln+32]; t3 *= rs * w[ln+48];
  int s = row & (kS - 1);
  const float* cp = cosb + (size_t)s*64;
  const float* sp = sinb + (size_t)s*64;
  float o0 = t0*cp[ln]    - t2*sp[ln];
  float o1 = t1*cp[ln+16] - t3*sp[ln+16];
  float o2 = t2*cp[ln+32] + t0*sp[ln+32];
  float o3 = t3*cp[ln+48] + t1*sp[ln+48];
  dst[ln]    = (__bf16)o0; dst[ln+16] = (__bf16)o1;
  dst[ln+32] = (__bf16)o2; dst[ln+48] = (__bf16)o3;
}

// ------------------------------------------------------------- windowed attention
// grid (64 strips, H=16, B=4), 64 threads (ONE wave) per block.
// strip = c*4+w covers q-rows strip*64..+63; key tiles kt = w..w+4 of the
// chunk window [c*256-128, c*256+383], each 64-aligned so OOB is all-or-nothing.
// K and V^T both read directly from global (L2-resident); only the P slice
// round-trips through 2.3 KB of LDS.
__global__ __launch_bounds__(64, 3) void k_attn2(const bf16_t* __restrict__ q,
                                                 const bf16_t* __restrict__ kbuf,
                                                 const bf16_t* __restrict__ vT,
                                                 bf16_t* __restrict__ o){
  __shared__ bf16_t Pm[16][72];
  const int strip = blockIdx.x, h = blockIdx.y, b = blockIdx.z;
  const int c = strip >> 2, w = strip & 3;
  const int hkv = h >> 2;
  const int lane = threadIdx.x;
  const int l15 = lane & 15, l4 = lane >> 4;
  const int qrow0 = strip*64;

  bf16x8 qf[4][2];
#pragma unroll
  for (int mt = 0; mt < 4; mt++)
#pragma unroll
    for (int ks = 0; ks < 2; ks++)
      qf[mt][ks] = *(const bf16x8*)(q + (size_t)(b*kS + qrow0 + mt*16 + l15)*1024
                                      + h*64 + ks*32 + l4*8);

  f32x4 acc[4][4];
  float m_run[4][4], l_run[4][4];
#pragma unroll
  for (int mt = 0; mt < 4; mt++){
#pragma unroll
    for (int dt = 0; dt < 4; dt++)
#pragma unroll
      for (int r = 0; r < 4; r++) acc[mt][dt][r] = 0.f;
#pragma unroll
    for (int r = 0; r < 4; r++){ m_run[mt][r] = -1e30f; l_run[mt][r] = 0.f; }
  }

  for (int kt = w; kt <= w + 4; kt++){
    const int kg0 = c*kChunk - 128 + kt*64;
    if (kg0 < 0 || kg0 >= kS) continue;     // 64-aligned tile fully OOB -> fully masked

    // ---- K fragments direct from global
    bf16x8 kf[4][2];
#pragma unroll
    for (int nt = 0; nt < 4; nt++){
      const bf16_t* kr = kbuf + (size_t)(b*kS + kg0 + nt*16 + l15)*256 + hkv*64;
#pragma unroll
      for (int ks = 0; ks < 2; ks++)
        kf[nt][ks] = *(const bf16x8*)(kr + ks*32 + l4*8);
    }
    // ---- V^T fragments direct from global: row dh = dt*16+l15, keys kg0+ks*32+l4*8..+7
    bf16x8 vf[2][4];
#pragma unroll
    for (int dt = 0; dt < 4; dt++){
      const bf16_t* vr = vT + (size_t)(b*256 + hkv*64 + dt*16 + l15)*4096 + kg0;
#pragma unroll
      for (int ks = 0; ks < 2; ks++)
        vf[ks][dt] = *(const bf16x8*)(vr + ks*32 + l4*8);
    }

#pragma unroll
    for (int mt = 0; mt < 4; mt++){
      f32x4 sc[4];
#pragma unroll
      for (int nt = 0; nt < 4; nt++)
#pragma unroll
        for (int r = 0; r < 4; r++) sc[nt][r] = 0.f;
#pragma unroll
      for (int ks = 0; ks < 2; ks++)
#pragma unroll
        for (int nt = 0; nt < 4; nt++)
          sc[nt] = MFMA_BF16(qf[mt][ks], kf[nt][ks], sc[nt]);

      const int qg0 = qrow0 + mt*16 + l4*4;
#pragma unroll
      for (int nt = 0; nt < 4; nt++){
        int kg = kg0 + nt*16 + l15;
#pragma unroll
        for (int r = 0; r < 4; r++){
          int rel = kg - (qg0 + r);
          bool okm = (rel >= -128) && (rel <= 128);
          sc[nt][r] = okm ? sc[nt][r]*0.125f : -1e30f;
        }
      }
      float mx[4], fct[4], rsum[4];
#pragma unroll
      for (int r = 0; r < 4; r++){
        mx[r] = fmaxf(fmaxf(sc[0][r], sc[1][r]), fmaxf(sc[2][r], sc[3][r]));
        mx[r] = fmaxf(mx[r], __shfl_xor(mx[r], 1));
        mx[r] = fmaxf(mx[r], __shfl_xor(mx[r], 2));
        mx[r] = fmaxf(mx[r], __shfl_xor(mx[r], 4));
        mx[r] = fmaxf(mx[r], __shfl_xor(mx[r], 8));
        float mn = fmaxf(m_run[mt][r], mx[r]);
        fct[r] = __expf(m_run[mt][r] - mn);
        m_run[mt][r] = mn;
        rsum[r] = 0.f;
      }
#pragma unroll
      for (int nt = 0; nt < 4; nt++)
#pragma unroll
        for (int r = 0; r < 4; r++){
          float p = __expf(sc[nt][r] - m_run[mt][r]);
          rsum[r] += p;
          sc[nt][r] = p;
        }
#pragma unroll
      for (int r = 0; r < 4; r++){
        rsum[r] += __shfl_xor(rsum[r], 1);
        rsum[r] += __shfl_xor(rsum[r], 2);
        rsum[r] += __shfl_xor(rsum[r], 4);
        rsum[r] += __shfl_xor(rsum[r], 8);
        l_run[mt][r] = l_run[mt][r]*fct[r] + rsum[r];
      }
#pragma unroll
      for (int dt = 0; dt < 4; dt++)
#pragma unroll
        for (int r = 0; r < 4; r++) acc[mt][dt][r] *= fct[r];

      // ---- P slice to LDS (rows l4*4+r, cols nt*16+l15)
#pragma unroll
      for (int nt = 0; nt < 4; nt++)
#pragma unroll
        for (int r = 0; r < 4; r++)
          Pm[l4*4 + r][nt*16 + l15] = (__bf16)sc[nt][r];

      lds_fence();   // P writes visible wave-wide

      // ---- PV for this mt: acc[mt][dt] += P16x64 @ V64x64
      bf16x8 pf0 = *(const bf16x8*)&Pm[l15][l4*8];
      bf16x8 pf1 = *(const bf16x8*)&Pm[l15][32 + l4*8];
#pragma unroll
      for (int dt = 0; dt < 4; dt++){
        acc[mt][dt] = MFMA_BF16(pf0, vf[0][dt], acc[mt][dt]);
        acc[mt][dt] = MFMA_BF16(pf1, vf[1][dt], acc[mt][dt]);
      }
      lds_fence();   // PV reads done before next mt overwrites Pm
    }
  }

#pragma unroll
  for (int mt = 0; mt < 4; mt++)
#pragma unroll
    for (int dt = 0; dt < 4; dt++){
      int row = b*kS + qrow0 + mt*16 + l4*4;
      int col = h*64 + dt*16 + l15;
#pragma unroll
      for (int r = 0; r < 4; r++){
        float ov = acc[mt][dt][r] / l_run[mt][r];
        o[(size_t)(row + r)*1024 + col] = (__bf16)ov;
      }
    }
}

// ---------------------------------------------------------------------- launch
extern "C" void kernel_launch(void* const* d_in, const int* in_sizes, int n_in,
                              void* d_out, int out_size, void* d_ws, size_t ws_size,
                              hipStream_t stream){
  (void)in_sizes; (void)n_in; (void)out_size; (void)ws_size;
  const float* x    = (const float*)d_in[0];
  const float* Wq   = (const float*)d_in[1];
  const float* bq   = (const float*)d_in[2];
  const float* Wk   = (const float*)d_in[3];
  const float* bk   = (const float*)d_in[4];
  const float* Wv   = (const float*)d_in[5];
  const float* bv   = (const float*)d_in[6];
  const float* Wo   = (const float*)d_in[7];
  const float* bo   = (const float*)d_in[8];
  const float* qn_w = (const float*)d_in[9];
  const float* kn_w = (const float*)d_in[10];
  const float* cosb = (const float*)d_in[11];
  const float* sinb = (const float*)d_in[12];
  float* out = (float*)d_out;

  char* ws = (char*)d_ws;
  const size_t MB = 1024ull*1024ull;
  bf16_t* x_b  = (bf16_t*)(ws);                    // 32 MB  [16384,1024]
  bf16_t* q_b  = (bf16_t*)(ws + 32*MB);            // 32 MB  [16384,1024]
  bf16_t* k_b  = (bf16_t*)(ws + 64*MB);            //  8 MB  [16384,256]
  bf16_t* v_b  = (bf16_t*)(ws + 72*MB);            //  8 MB  [16384,256]
  float*  k_f  = (float*) (ws + 80*MB);            // 16 MB  [16384,256]
  bf16_t* wq_t = (bf16_t*)(ws + 96*MB);            //  2 MB  [1024,1024]
  bf16_t* wo_t = (bf16_t*)(ws + 98*MB);            //  2 MB  [1024,1024]
  bf16_t* wk_t = (bf16_t*)(ws + 100*MB);           // .5 MB  [256,1024]
  bf16_t* wv_t = (bf16_t*)(ws + 100*MB + 512*1024);// .5 MB  [256,1024]
  bf16_t* vT_b = (bf16_t*)(ws + 101*MB);           //  8 MB  [1024,4096] V^T
  bf16_t* attn_b = x_b;     // reuse: x_b dead after QKV GEMMs
  float*  q_f  = out;       // reuse d_out as q-f32 scratch (overwritten at end)

  k_cvt_bf16<<<dim3(16384), dim3(256), 0, stream>>>(x, x_b, (kB*kS*kD)/4);
  k_transpose_cvt<<<dim3(32, 32), dim3(256), 0, stream>>>(Wq, wq_t, 1024, 1024);
  k_transpose_cvt<<<dim3(8, 32),  dim3(256), 0, stream>>>(Wk, wk_t, 1024, 256);
  k_transpose_cvt<<<dim3(8, 32),  dim3(256), 0, stream>>>(Wv, wv_t, 1024, 256);
  k_transpose_cvt<<<dim3(32, 32), dim3(256), 0, stream>>>(Wo, wo_t, 1024, 1024);

  k_gemm_bt<false><<<dim3(8, 128), dim3(256), 0, stream>>>(x_b, wq_t, bq, (void*)q_f, 16384, 1024, 1024);
  k_gemm_bt<false><<<dim3(2, 128), dim3(256), 0, stream>>>(x_b, wk_t, bk, (void*)k_f, 16384, 256, 1024);
  k_gemm_bt<true ><<<dim3(2, 128), dim3(256), 0, stream>>>(x_b, wv_t, bv, (void*)v_b, 16384, 256, 1024);

  k_norm_rope<<<dim3(20480), dim3(256), 0, stream>>>(q_f, k_f, qn_w, kn_w, cosb, sinb, q_b, k_b);
  k_transpose_v<<<dim3(512, 8), dim3(256), 0, stream>>>(v_b, vT_b);

  k_attn2<<<dim3(64, 16, 4), dim3(64), 0, stream>>>(q_b, k_b, vT_b, attn_b);

  k_gemm_bt<false><<<dim3(8, 128), dim3(256), 0, stream>>>(attn_b, wo_t, bo, (void*)out, 16384, 1024, 1024);
}

// Round 9
// 391.489 us; speedup vs baseline: 1.3141x; 1.3141x over previous
//
#include <hip/hip_runtime.h>
#include <stdint.h>

typedef __bf16 bf16_t;
typedef __bf16 bf16x8 __attribute__((ext_vector_type(8)));
typedef __bf16 bf16x4 __attribute__((ext_vector_type(4)));
typedef float  f32x4  __attribute__((ext_vector_type(4)));

#define MFMA_BF16(a,b,c) __builtin_amdgcn_mfma_f32_16x16x32_bf16((a),(b),(c),0,0,0)

constexpr int kB = 4;
constexpr int kS = 4096;
constexpr int kD = 1024;
constexpr int kH = 16;
constexpr int kHKV = 4;
constexpr int kDH = 64;
constexpr int kChunk = 256;

// wave-internal LDS write->read fence (no cross-wave sync needed)
__device__ __forceinline__ void lds_fence(){
  asm volatile("s_waitcnt lgkmcnt(0)" ::: "memory");
  __builtin_amdgcn_sched_barrier(0);
}

// ---------------------------------------------------------------- f32 -> bf16
__global__ __launch_bounds__(256) void k_cvt_bf16(const float* __restrict__ in,
                                                  bf16_t* __restrict__ out, int n4){
  int i = blockIdx.x * 256 + threadIdx.x;
  if (i >= n4) return;
  float4 v = ((const float4*)in)[i];
  bf16x4 o;
  o[0] = (__bf16)v.x; o[1] = (__bf16)v.y; o[2] = (__bf16)v.z; o[3] = (__bf16)v.w;
  ((bf16x4*)out)[i] = o;
}

// ------------------------------------------------- W[K,N] f32 -> Wt[N,K] bf16
__global__ __launch_bounds__(256) void k_transpose_cvt(const float* __restrict__ W,
                                                       bf16_t* __restrict__ Wt,
                                                       int K, int N){
  __shared__ float t[32][33];
  int n0 = blockIdx.x * 32, k0 = blockIdx.y * 32;
  int tx = threadIdx.x & 31, ty = threadIdx.x >> 5;
#pragma unroll
  for (int i = 0; i < 4; i++){
    int kkk = ty + i*8;
    t[kkk][tx] = W[(size_t)(k0+kkk)*N + n0 + tx];
  }
  __syncthreads();
#pragma unroll
  for (int i = 0; i < 4; i++){
    int nn = ty + i*8;
    Wt[(size_t)(n0+nn)*K + k0 + tx] = (__bf16)t[tx][nn];
  }
}

// ------------------------------------- V [B*S, HKV*64] bf16 -> vT [B*256 rows][S] bf16
// out row (b*256 + col) holds V^T: vT[(b*256+hkv*64+dh)*4096 + s] = V[b,s,hkv,dh]
__global__ __launch_bounds__(256) void k_transpose_v(const bf16_t* __restrict__ V,
                                                     bf16_t* __restrict__ vT){
  __shared__ bf16_t t[32][36];
  int r0 = blockIdx.x * 32;              // global row (b*4096+s), 512 tiles
  int c0 = blockIdx.y * 32;              // col (hkv*64+dh), 8 tiles
  int tx = threadIdx.x & 31, ty = threadIdx.x >> 5;
  int b  = r0 >> 12, s0 = r0 & 4095;
#pragma unroll
  for (int i = 0; i < 4; i++)
    t[ty + i*8][tx] = V[(size_t)(r0 + ty + i*8)*256 + c0 + tx];
  __syncthreads();
#pragma unroll
  for (int i = 0; i < 4; i++){
    int cc = ty + i*8;
    vT[(size_t)(b*256 + c0 + cc)*4096 + s0 + tx] = t[tx][cc];
  }
}

// --------------------------------------------------------- GEMM: A[M,K]@Bt[N,K]^T + bias
// round-1 form (measured faster than gload_lds variant by ~40us total):
// 128x128 tile, BK=64, reg-staged bf16x8 loads into padded [128][72] LDS.
template<bool BF16OUT>
__global__ __launch_bounds__(256) void k_gemm_bt(const bf16_t* __restrict__ A,
                                                 const bf16_t* __restrict__ Bt,
                                                 const float* __restrict__ bias,
                                                 void* __restrict__ outp,
                                                 int M, int N, int K){
  (void)M;
  __shared__ bf16_t Al[128][72];
  __shared__ bf16_t Bl[128][72];
  const int tid = threadIdx.x;
  const int lane = tid & 63;
  const int wave = tid >> 6;
  const int wm = wave >> 1, wn = wave & 1;
  const int bm = blockIdx.y, bn = blockIdx.x;
  const int l15 = lane & 15, l4 = lane >> 4;
  f32x4 acc[4][4];
#pragma unroll
  for (int a = 0; a < 4; a++)
#pragma unroll
    for (int b = 0; b < 4; b++)
#pragma unroll
      for (int r = 0; r < 4; r++) acc[a][b][r] = 0.f;

  for (int kt = 0; kt < K; kt += 64){
    __syncthreads();
#pragma unroll
    for (int i = 0; i < 4; i++){
      int task = i*256 + tid;
      int rr = task >> 3, c8 = task & 7;
      *(bf16x8*)&Al[rr][c8*8] = *(const bf16x8*)(A + (size_t)(bm*128 + rr)*K + kt + c8*8);
      *(bf16x8*)&Bl[rr][c8*8] = *(const bf16x8*)(Bt + (size_t)(bn*128 + rr)*K + kt + c8*8);
    }
    __syncthreads();
#pragma unroll
    for (int ks = 0; ks < 2; ks++){
      bf16x8 af[4], bfr[4];
#pragma unroll
      for (int mt = 0; mt < 4; mt++) af[mt]  = *(const bf16x8*)&Al[wm*64 + mt*16 + l15][ks*32 + l4*8];
#pragma unroll
      for (int nt = 0; nt < 4; nt++) bfr[nt] = *(const bf16x8*)&Bl[wn*64 + nt*16 + l15][ks*32 + l4*8];
#pragma unroll
      for (int mt = 0; mt < 4; mt++)
#pragma unroll
        for (int nt = 0; nt < 4; nt++)
          acc[mt][nt] = MFMA_BF16(af[mt], bfr[nt], acc[mt][nt]);
    }
  }
#pragma unroll
  for (int mt = 0; mt < 4; mt++){
#pragma unroll
    for (int nt = 0; nt < 4; nt++){
      int row0 = bm*128 + wm*64 + mt*16 + l4*4;
      int col  = bn*128 + wn*64 + nt*16 + l15;
      float bv = bias[col];
#pragma unroll
      for (int r = 0; r < 4; r++){
        float v = acc[mt][nt][r] + bv;
        if (BF16OUT) ((bf16_t*)outp)[(size_t)(row0 + r)*N + col] = (__bf16)v;
        else         ((float*)outp)[(size_t)(row0 + r)*N + col] = v;
      }
    }
  }
}

// -------------------------------------------- RMSNorm + RoPE (q and k), f32 -> bf16
__global__ __launch_bounds__(256) void k_norm_rope(const float* __restrict__ qin,
                                                   const float* __restrict__ kin,
                                                   const float* __restrict__ qw,
                                                   const float* __restrict__ kw,
                                                   const float* __restrict__ cosb,
                                                   const float* __restrict__ sinb,
                                                   bf16_t* __restrict__ qout,
                                                   bf16_t* __restrict__ kout){
  const int g = blockIdx.x * 16 + (threadIdx.x >> 4);
  const int ln = threadIdx.x & 15;
  const int NQ = (kB*kS) * kH;
  const float* src; bf16_t* dst; const float* w;
  int row;
  if (g < NQ){
    row = g >> 4; int head = g & 15;
    src = qin + (size_t)row*1024 + head*64;
    dst = qout + (size_t)row*1024 + head*64;
    w = qw;
  } else {
    int gk = g - NQ;
    row = gk >> 2; int head = gk & 3;
    src = kin + (size_t)row*256 + head*64;
    dst = kout + (size_t)row*256 + head*64;
    w = kw;
  }
  float t0 = src[ln], t1 = src[ln+16], t2 = src[ln+32], t3 = src[ln+48];
  float ss = t0*t0 + t1*t1 + t2*t2 + t3*t3;
  ss += __shfl_xor(ss, 1); ss += __shfl_xor(ss, 2);
  ss += __shfl_xor(ss, 4); ss += __shfl_xor(ss, 8);
  float rs = rsqrtf(ss * (1.0f/64.0f) + 1e-6f);
  t0 *= rs * w[ln];    t1 *= rs * w[ln+16];
  t2 *= rs * w[ln+32]; t3 *= rs * w[ln+48];
  int s = row & (kS - 1);
  const float* cp = cosb + (size_t)s*64;
  const float* sp = sinb + (size_t)s*64;
  float o0 = t0*cp[ln]    - t2*sp[ln];
  float o1 = t1*cp[ln+16] - t3*sp[ln+16];
  float o2 = t2*cp[ln+32] + t0*sp[ln+32];
  float o3 = t3*cp[ln+48] + t1*sp[ln+48];
  dst[ln]    = (__bf16)o0; dst[ln+16] = (__bf16)o1;
  dst[ln+32] = (__bf16)o2; dst[ln+48] = (__bf16)o3;
}

// ------------------------------------------------------------- windowed attention
// grid (64 strips, H=16, B=4), 64 threads (ONE wave) per block.
// strip = c*4+w covers q-rows strip*64..+63; key tiles kt = w..w+4 of the
// chunk window [c*256-128, c*256+383], each 64-aligned so OOB is all-or-nothing.
// K and V^T both read directly from global (L2-resident); only the P slice
// round-trips through 2.3 KB of LDS.
// launch_bounds (64,2): VGPR cap ~256 >= ~200 demand -> NO SPILL (r8: (64,3)
// capped at 84 VGPR and spilled 600+ MB/dispatch to scratch).
__global__ __launch_bounds__(64, 2) void k_attn2(const bf16_t* __restrict__ q,
                                                 const bf16_t* __restrict__ kbuf,
                                                 const bf16_t* __restrict__ vT,
                                                 bf16_t* __restrict__ o){
  __shared__ bf16_t Pm[16][72];
  const int strip = blockIdx.x, h = blockIdx.y, b = blockIdx.z;
  const int c = strip >> 2, w = strip & 3;
  const int hkv = h >> 2;
  const int lane = threadIdx.x;
  const int l15 = lane & 15, l4 = lane >> 4;
  const int qrow0 = strip*64;

  bf16x8 qf[4][2];
#pragma unroll
  for (int mt = 0; mt < 4; mt++)
#pragma unroll
    for (int ks = 0; ks < 2; ks++)
      qf[mt][ks] = *(const bf16x8*)(q + (size_t)(b*kS + qrow0 + mt*16 + l15)*1024
                                      + h*64 + ks*32 + l4*8);

  f32x4 acc[4][4];
  float m_run[4][4], l_run[4][4];
#pragma unroll
  for (int mt = 0; mt < 4; mt++){
#pragma unroll
    for (int dt = 0; dt < 4; dt++)
#pragma unroll
      for (int r = 0; r < 4; r++) acc[mt][dt][r] = 0.f;
#pragma unroll
    for (int r = 0; r < 4; r++){ m_run[mt][r] = -1e30f; l_run[mt][r] = 0.f; }
  }

  for (int kt = w; kt <= w + 4; kt++){
    const int kg0 = c*kChunk - 128 + kt*64;
    if (kg0 < 0 || kg0 >= kS) continue;     // 64-aligned tile fully OOB -> fully masked

    // ---- K fragments direct from global
    bf16x8 kf[4][2];
#pragma unroll
    for (int nt = 0; nt < 4; nt++){
      const bf16_t* kr = kbuf + (size_t)(b*kS + kg0 + nt*16 + l15)*256 + hkv*64;
#pragma unroll
      for (int ks = 0; ks < 2; ks++)
        kf[nt][ks] = *(const bf16x8*)(kr + ks*32 + l4*8);
    }
    // ---- V^T fragments direct from global: row dh = dt*16+l15, keys kg0+ks*32+l4*8..+7
    bf16x8 vf[2][4];
#pragma unroll
    for (int dt = 0; dt < 4; dt++){
      const bf16_t* vr = vT + (size_t)(b*256 + hkv*64 + dt*16 + l15)*4096 + kg0;
#pragma unroll
      for (int ks = 0; ks < 2; ks++)
        vf[ks][dt] = *(const bf16x8*)(vr + ks*32 + l4*8);
    }

#pragma unroll
    for (int mt = 0; mt < 4; mt++){
      f32x4 sc[4];
#pragma unroll
      for (int nt = 0; nt < 4; nt++)
#pragma unroll
        for (int r = 0; r < 4; r++) sc[nt][r] = 0.f;
#pragma unroll
      for (int ks = 0; ks < 2; ks++)
#pragma unroll
        for (int nt = 0; nt < 4; nt++)
          sc[nt] = MFMA_BF16(qf[mt][ks], kf[nt][ks], sc[nt]);

      const int qg0 = qrow0 + mt*16 + l4*4;
#pragma unroll
      for (int nt = 0; nt < 4; nt++){
        int kg = kg0 + nt*16 + l15;
#pragma unroll
        for (int r = 0; r < 4; r++){
          int rel = kg - (qg0 + r);
          bool okm = (rel >= -128) && (rel <= 128);
          sc[nt][r] = okm ? sc[nt][r]*0.125f : -1e30f;
        }
      }
      float mx[4], fct[4], rsum[4];
#pragma unroll
      for (int r = 0; r < 4; r++){
        mx[r] = fmaxf(fmaxf(sc[0][r], sc[1][r]), fmaxf(sc[2][r], sc[3][r]));
        mx[r] = fmaxf(mx[r], __shfl_xor(mx[r], 1));
        mx[r] = fmaxf(mx[r], __shfl_xor(mx[r], 2));
        mx[r] = fmaxf(mx[r], __shfl_xor(mx[r], 4));
        mx[r] = fmaxf(mx[r], __shfl_xor(mx[r], 8));
        float mn = fmaxf(m_run[mt][r], mx[r]);
        fct[r] = __expf(m_run[mt][r] - mn);
        m_run[mt][r] = mn;
        rsum[r] = 0.f;
      }
#pragma unroll
      for (int nt = 0; nt < 4; nt++)
#pragma unroll
        for (int r = 0; r < 4; r++){
          float p = __expf(sc[nt][r] - m_run[mt][r]);
          rsum[r] += p;
          sc[nt][r] = p;
        }
#pragma unroll
      for (int r = 0; r < 4; r++){
        rsum[r] += __shfl_xor(rsum[r], 1);
        rsum[r] += __shfl_xor(rsum[r], 2);
        rsum[r] += __shfl_xor(rsum[r], 4);
        rsum[r] += __shfl_xor(rsum[r], 8);
        l_run[mt][r] = l_run[mt][r]*fct[r] + rsum[r];
      }
#pragma unroll
      for (int dt = 0; dt < 4; dt++)
#pragma unroll
        for (int r = 0; r < 4; r++) acc[mt][dt][r] *= fct[r];

      // ---- P slice to LDS (rows l4*4+r, cols nt*16+l15)
#pragma unroll
      for (int nt = 0; nt < 4; nt++)
#pragma unroll
        for (int r = 0; r < 4; r++)
          Pm[l4*4 + r][nt*16 + l15] = (__bf16)sc[nt][r];

      lds_fence();   // P writes visible wave-wide

      // ---- PV for this mt: acc[mt][dt] += P16x64 @ V64x64
      bf16x8 pf0 = *(const bf16x8*)&Pm[l15][l4*8];
      bf16x8 pf1 = *(const bf16x8*)&Pm[l15][32 + l4*8];
#pragma unroll
      for (int dt = 0; dt < 4; dt++){
        acc[mt][dt] = MFMA_BF16(pf0, vf[0][dt], acc[mt][dt]);
        acc[mt][dt] = MFMA_BF16(pf1, vf[1][dt], acc[mt][dt]);
      }
      lds_fence();   // PV reads done before next mt overwrites Pm
    }
  }

#pragma unroll
  for (int mt = 0; mt < 4; mt++)
#pragma unroll
    for (int dt = 0; dt < 4; dt++){
      int row = b*kS + qrow0 + mt*16 + l4*4;
      int col = h*64 + dt*16 + l15;
#pragma unroll
      for (int r = 0; r < 4; r++){
        float ov = acc[mt][dt][r] / l_run[mt][r];
        o[(size_t)(row + r)*1024 + col] = (__bf16)ov;
      }
    }
}

// ---------------------------------------------------------------------- launch
extern "C" void kernel_launch(void* const* d_in, const int* in_sizes, int n_in,
                              void* d_out, int out_size, void* d_ws, size_t ws_size,
                              hipStream_t stream){
  (void)in_sizes; (void)n_in; (void)out_size; (void)ws_size;
  const float* x    = (const float*)d_in[0];
  const float* Wq   = (const float*)d_in[1];
  const float* bq   = (const float*)d_in[2];
  const float* Wk   = (const float*)d_in[3];
  const float* bk   = (const float*)d_in[4];
  const float* Wv   = (const float*)d_in[5];
  const float* bv   = (const float*)d_in[6];
  const float* Wo   = (const float*)d_in[7];
  const float* bo   = (const float*)d_in[8];
  const float* qn_w = (const float*)d_in[9];
  const float* kn_w = (const float*)d_in[10];
  const float* cosb = (const float*)d_in[11];
  const float* sinb = (const float*)d_in[12];
  float* out = (float*)d_out;

  char* ws = (char*)d_ws;
  const size_t MB = 1024ull*1024ull;
  bf16_t* x_b  = (bf16_t*)(ws);                    // 32 MB  [16384,1024]
  bf16_t* q_b  = (bf16_t*)(ws + 32*MB);            // 32 MB  [16384,1024]
  bf16_t* k_b  = (bf16_t*)(ws + 64*MB);            //  8 MB  [16384,256]
  bf16_t* v_b  = (bf16_t*)(ws + 72*MB);            //  8 MB  [16384,256]
  float*  k_f  = (float*) (ws + 80*MB);            // 16 MB  [16384,256]
  bf16_t* wq_t = (bf16_t*)(ws + 96*MB);            //  2 MB  [1024,1024]
  bf16_t* wo_t = (bf16_t*)(ws + 98*MB);            //  2 MB  [1024,1024]
  bf16_t* wk_t = (bf16_t*)(ws + 100*MB);           // .5 MB  [256,1024]
  bf16_t* wv_t = (bf16_t*)(ws + 100*MB + 512*1024);// .5 MB  [256,1024]
  bf16_t* vT_b = (bf16_t*)(ws + 101*MB);           //  8 MB  [1024,4096] V^T
  bf16_t* attn_b = x_b;     // reuse: x_b dead after QKV GEMMs
  float*  q_f  = out;       // reuse d_out as q-f32 scratch (overwritten at end)

  k_cvt_bf16<<<dim3(16384), dim3(256), 0, stream>>>(x, x_b, (kB*kS*kD)/4);
  k_transpose_cvt<<<dim3(32, 32), dim3(256), 0, stream>>>(Wq, wq_t, 1024, 1024);
  k_transpose_cvt<<<dim3(8, 32),  dim3(256), 0, stream>>>(Wk, wk_t, 1024, 256);
  k_transpose_cvt<<<dim3(8, 32),  dim3(256), 0, stream>>>(Wv, wv_t, 1024, 256);
  k_transpose_cvt<<<dim3(32, 32), dim3(256), 0, stream>>>(Wo, wo_t, 1024, 1024);

  k_gemm_bt<false><<<dim3(8, 128), dim3(256), 0, stream>>>(x_b, wq_t, bq, (void*)q_f, 16384, 1024, 1024);
  k_gemm_bt<false><<<dim3(2, 128), dim3(256), 0, stream>>>(x_b, wk_t, bk, (void*)k_f, 16384, 256, 1024);
  k_gemm_bt<true ><<<dim3(2, 128), dim3(256), 0, stream>>>(x_b, wv_t, bv, (void*)v_b, 16384, 256, 1024);

  k_norm_rope<<<dim3(20480), dim3(256), 0, stream>>>(q_f, k_f, qn_w, kn_w, cosb, sinb, q_b, k_b);
  k_transpose_v<<<dim3(512, 8), dim3(256), 0, stream>>>(v_b, vT_b);

  k_attn2<<<dim3(64, 16, 4), dim3(64), 0, stream>>>(q_b, k_b, vT_b, attn_b);

  k_gemm_bt<false><<<dim3(8, 128), dim3(256), 0, stream>>>(attn_b, wo_t, bo, (void*)out, 16384, 1024, 1024);
}